// Round 2
// baseline (2448.493 us; speedup 1.0000x reference)
//
#include <hip/hip_runtime.h>
#include <math.h>

#define Bn 64
#define Tn 2048
#define Hn 256
#define NIc 4
#define NAc 2

constexpr float LEAK    = 0.5f;     // 1 - 1/TAU
constexpr float NEGDIAG = -0.5f;    // -1/TAU
constexpr float CLAMP_V = 1000.0f;
constexpr float EPS_V   = 1e-4f;

// ---------------------------------------------------------------------------
// K1: u[r, j] = sum_k relu( inp8[r] . W1[k] + b1[k] ) * Wih[j][k]
//     r = t*B + b (row of the (T,B,H) tensor), 64 rows/block, j = threadIdx.
// ---------------------------------------------------------------------------
__global__ __launch_bounds__(256) void k_u(
    const float* __restrict__ reward, const float* __restrict__ state,
    const float* __restrict__ last_action, const float* __restrict__ W1,
    const float* __restrict__ b1, const float* __restrict__ Wih,
    float* __restrict__ u)
{
  __shared__ float inp_s[64][8];
  __shared__ float w1_s[256][8];
  __shared__ float b1_s[256];
  __shared__ __align__(16) float x_s[32][68];   // [kk][rr], padded
  __shared__ float w_s[32][257];                // [kk][j],  padded
  const int tid = threadIdx.x;
  const int r0  = blockIdx.x * 64;

  for (int idx = tid; idx < 2048; idx += 256) ((float*)w1_s)[idx] = W1[idx];
  b1_s[tid] = b1[tid];
  for (int idx = tid; idx < 512; idx += 256) {
    int rr = idx >> 3, i = idx & 7;
    int r = r0 + rr; int b = r & (Bn - 1); int t = r >> 6;
    long base = (long)b * Tn + t;
    float v;
    if (i < NAc)            v = reward[base * NAc + i];
    else if (i < NAc + NIc) v = state[base * NIc + (i - NAc)];
    else                    v = last_action[base * NAc + (i - NAc - NIc)];
    inp_s[rr][i] = v;
  }

  float acc[64];
  #pragma unroll
  for (int rr = 0; rr < 64; ++rr) acc[rr] = 0.f;

  for (int c = 0; c < 8; ++c) {
    const int k0 = c * 32;
    __syncthreads();
    for (int idx = tid; idx < 8192; idx += 256) {      // Wih chunk, transposed
      int j = idx >> 5, kk = idx & 31;
      w_s[kk][j] = Wih[j * 256 + k0 + kk];
    }
    for (int idx = tid; idx < 2048; idx += 256) {      // x chunk on the fly
      int kk = idx & 31, rr = idx >> 5;
      int k = k0 + kk;
      float s = b1_s[k];
      #pragma unroll
      for (int i = 0; i < 8; ++i) s = fmaf(inp_s[rr][i], w1_s[k][i], s);
      x_s[kk][rr] = fmaxf(s, 0.f);
    }
    __syncthreads();
    #pragma unroll
    for (int kk = 0; kk < 32; ++kk) {
      float wv = w_s[kk][tid];
      const float4* xp = reinterpret_cast<const float4*>(&x_s[kk][0]);
      #pragma unroll
      for (int q = 0; q < 16; ++q) {
        float4 xv = xp[q];
        acc[4*q+0] = fmaf(xv.x, wv, acc[4*q+0]);
        acc[4*q+1] = fmaf(xv.y, wv, acc[4*q+1]);
        acc[4*q+2] = fmaf(xv.z, wv, acc[4*q+2]);
        acc[4*q+3] = fmaf(xv.w, wv, acc[4*q+3]);
      }
    }
  }
  for (int rr = 0; rr < 64; ++rr)
    u[(long)(r0 + rr) * Hn + tid] = acc[rr];
}

// ---------------------------------------------------------------------------
// K2 v2: sequential scan, LDS-traffic-minimized.
// 1 block / batch row, 512 threads = 8 waves. Wave w owns outputs
// j in [32w, 32w+32). Lane l = o*16+g (o in [0,4), g in [0,16)) computes
// partials for 8 outputs j = 32w+8o+m over k-slice [16g,16g+16):
//   - weights 8x16 in VGPRs (static indexing)
//   - rh read: 4x ds_read_b128 (rotation-swizzled, 2-way max per bank)
//   - reduce-scatter over the 16 g-lanes via 4 shfl_xor stages
//   - owner lane (g<8, m = bitrev-ish(g)) updates h, writes ys + next rh
// One barrier per step; rh double-buffered (WAR-safe: a wave reaching the
// write of buffer p passed the barrier at which all reads of p-from-2-steps-
// ago were drained).
// LDS/step: 32KB read + 1KB write  (was 256KB)  -> VALU-bound at ~128 FMA/thr.
// ---------------------------------------------------------------------------
__global__ __launch_bounds__(512) void k_scan(
    const float* __restrict__ Whh_raw, const float* __restrict__ hidden_in,
    float* __restrict__ ubuf, float* __restrict__ out)
{
  __shared__ __align__(16) float rh[2][256];
  const int tid = threadIdx.x;
  const int w = tid >> 6;
  const int l = tid & 63;
  const int g = l & 15;          // k-group
  const int o = l >> 4;          // output sub-group
  const int b = blockIdx.x;
  const int kbase = g << 4;

  // per-thread weights: 8 outputs x 16 k
  float wgt[8][16];
  #pragma unroll
  for (int m = 0; m < 8; ++m) {
    const int j = (w << 5) + (o << 3) + m;
    #pragma unroll
    for (int i = 0; i < 16; ++i) {
      const int k = kbase + i;
      float v = Whh_raw[j * 256 + k];
      wgt[m][i] = (k == j) ? NEGDIAG : v;
    }
  }

  // ownership: lanes with g<8 own output m = 4*b0 + 2*b1 + b2 (reduce-scatter end)
  const int b0 = g & 1, b1 = (g >> 1) & 1, b2 = (g >> 2) & 1, b3 = (g >> 3) & 1;
  const bool owner = (b3 == 0);
  const int m_own = (b0 << 2) | (b1 << 1) | b2;
  const int j_own = (w << 5) + (o << 3) + m_own;

  // swizzle: float index k -> (k & ~15) | ((((k>>2)&3) + (k>>4)) & 3) << 2 | (k&3)
  const int wr_off = (j_own & ~15) | (((((j_own >> 2) & 3) + (j_own >> 4)) & 3) << 2) | (j_own & 3);
  int rd_off[4];
  #pragma unroll
  for (int q = 0; q < 4; ++q) rd_off[q] = (g << 4) + (((q + g) & 3) << 2);

  float h = 0.f, u_cur = 0.f;
  if (owner) {
    h     = hidden_in[b * Hn + j_own];
    u_cur = ubuf[b * Hn + j_own];                 // u[t=0]
  }
  const float* u_ptr  = ubuf + (long)(1 * Bn + b) * Hn + j_own;   // prefetch t=1
  float*       ys_ptr = ubuf + (long)(0 * Bn + b) * Hn + j_own;   // write t=0

  for (int t = 0; t < Tn; ++t) {
    const int p = t & 1;
    if (owner) rh[p][wr_off] = fmaxf(h, 0.f);
    __syncthreads();

    float u_nxt = 0.f;
    if (owner && t < Tn - 1) u_nxt = *u_ptr;      // hide HBM latency under FMAs

    float v[8];
    #pragma unroll
    for (int m = 0; m < 8; ++m) v[m] = 0.f;
    #pragma unroll
    for (int q = 0; q < 4; ++q) {
      const float4 r4 = *reinterpret_cast<const float4*>(&rh[p][rd_off[q]]);
      #pragma unroll
      for (int m = 0; m < 8; ++m) {
        v[m] = fmaf(r4.x, wgt[m][4*q+0], v[m]);
        v[m] = fmaf(r4.y, wgt[m][4*q+1], v[m]);
        v[m] = fmaf(r4.z, wgt[m][4*q+2], v[m]);
        v[m] = fmaf(r4.w, wgt[m][4*q+3], v[m]);
      }
    }

    // reduce-scatter over g (xor 1,2,4 pick halves; xor 8 final all-reduce)
    float t0[4];
    #pragma unroll
    for (int i = 0; i < 4; ++i) {
      const float send = b0 ? v[i] : v[i + 4];
      const float keep = b0 ? v[i + 4] : v[i];
      t0[i] = keep + __shfl_xor(send, 1);
    }
    float t1[2];
    #pragma unroll
    for (int i = 0; i < 2; ++i) {
      const float send = b1 ? t0[i] : t0[i + 2];
      const float keep = b1 ? t0[i + 2] : t0[i];
      t1[i] = keep + __shfl_xor(send, 2);
    }
    const float send2 = b2 ? t1[0] : t1[1];
    const float keep2 = b2 ? t1[1] : t1[0];
    float s = keep2 + __shfl_xor(send2, 4);
    s += __shfl_xor(s, 8);

    if (owner) {
      float hn = fmaf(LEAK, h, u_cur) + s;
      hn = fminf(fmaxf(hn, -CLAMP_V), CLAMP_V);
      *ys_ptr = hn;                                // ys in place
      h = hn; u_cur = u_nxt;
    }
    ys_ptr += Bn * Hn;
    u_ptr  += Bn * Hn;
  }
  if (owner) out[(long)Bn * Tn * NAc + b * Hn + j_own] = h;
}

// ---------------------------------------------------------------------------
// K3: v = relu(ys @ W2^T + b2); y = v @ W3^T + b3; softmax/mix epilogue.
// ---------------------------------------------------------------------------
__global__ __launch_bounds__(256) void k_out(
    const float* __restrict__ ys, const float* __restrict__ W2,
    const float* __restrict__ b2, const float* __restrict__ W3,
    const float* __restrict__ b3, const float* __restrict__ Qs,
    const float* __restrict__ reward, const float* __restrict__ mix_w,
    float* __restrict__ out)
{
  __shared__ __align__(16) float a_s[32][68];
  __shared__ float w_s[32][257];
  __shared__ float part_s[4][64][2];
  const int tid = threadIdx.x;
  const int r0  = blockIdx.x * 64;
  const float b2v = b2[tid];
  const float w3a = W3[tid];
  const float w3b = W3[256 + tid];

  float acc[64];
  #pragma unroll
  for (int rr = 0; rr < 64; ++rr) acc[rr] = 0.f;

  for (int c = 0; c < 8; ++c) {
    const int k0 = c * 32;
    __syncthreads();
    for (int idx = tid; idx < 8192; idx += 256) {
      int jj = idx >> 5, kk = idx & 31;
      w_s[kk][jj] = W2[jj * 256 + k0 + kk];
    }
    for (int idx = tid; idx < 2048; idx += 256) {
      int kk = idx & 31, rr = idx >> 5;
      a_s[kk][rr] = ys[(long)(r0 + rr) * Hn + k0 + kk];
    }
    __syncthreads();
    #pragma unroll
    for (int kk = 0; kk < 32; ++kk) {
      float wv = w_s[kk][tid];
      const float4* xp = reinterpret_cast<const float4*>(&a_s[kk][0]);
      #pragma unroll
      for (int q = 0; q < 16; ++q) {
        float4 xv = xp[q];
        acc[4*q+0] = fmaf(xv.x, wv, acc[4*q+0]);
        acc[4*q+1] = fmaf(xv.y, wv, acc[4*q+1]);
        acc[4*q+2] = fmaf(xv.z, wv, acc[4*q+2]);
        acc[4*q+3] = fmaf(xv.w, wv, acc[4*q+3]);
      }
    }
  }

  const int lane = tid & 63, wid = tid >> 6;
  for (int rr = 0; rr < 64; ++rr) {
    float v  = fmaxf(acc[rr] + b2v, 0.f);
    float p0 = v * w3a;
    float p1 = v * w3b;
    #pragma unroll
    for (int off = 32; off; off >>= 1) {
      p0 += __shfl_xor(p0, off);
      p1 += __shfl_xor(p1, off);
    }
    if (lane == 0) { part_s[wid][rr][0] = p0; part_s[wid][rr][1] = p1; }
  }
  __syncthreads();

  if (tid < 128) {
    int rr = tid >> 1, a = tid & 1;
    float y = part_s[0][rr][a] + part_s[1][rr][a]
            + part_s[2][rr][a] + part_s[3][rr][a] + b3[a];
    int r = r0 + rr;
    int t = r >> 6, b = r & (Bn - 1);
    float z = (y == 0.f) ? EPS_V : 0.f;

    float y2 = __shfl_xor(y, 1);
    float m  = fmaxf(y, y2);
    float e  = expf(y - m), e2 = expf(y2 - m);
    float sp = e / (e + e2);

    long qi = ((long)b * Tn + t) * NAc + a;
    float qv = Qs[qi];
    float q2 = __shfl_xor(qv, 1);
    float mq = fmaxf(qv, q2);
    float eq = expf(qv - mq), eq2 = expf(q2 - mq);
    float sq = eq / (eq + eq2);

    int ri = (int)reward[((long)b * Tn + t) * NAc];
    float m0 = fminf(fmaxf(mix_w[ri * 2 + 0], -1.f), 1.f);
    float m1 = fminf(fmaxf(mix_w[ri * 2 + 1], -1.f), 1.f);
    float den = fabsf(m0) + fabsf(m1);
    float sel0 = m0 / den, sel1 = m1 / den;

    float mixed = sel0 * logf(sp + z) + sel1 * logf(sq + z);
    out[((long)b * Tn + t) * NAc + a] = expf(mixed);
  }
}

// ---------------------------------------------------------------------------
extern "C" void kernel_launch(void* const* d_in, const int* in_sizes, int n_in,
                              void* d_out, int out_size, void* d_ws, size_t ws_size,
                              hipStream_t stream)
{
  const float* state       = (const float*)d_in[0];
  const float* last_action = (const float*)d_in[1];
  const float* reward      = (const float*)d_in[2];
  const float* hidden_in   = (const float*)d_in[3];
  const float* W1          = (const float*)d_in[4];
  const float* b1          = (const float*)d_in[5];
  const float* Wih         = (const float*)d_in[6];
  const float* Whh_raw     = (const float*)d_in[7];
  const float* W2          = (const float*)d_in[8];
  const float* b2          = (const float*)d_in[9];
  const float* W3          = (const float*)d_in[10];
  const float* b3          = (const float*)d_in[11];
  const float* Qs          = (const float*)d_in[12];
  const float* mix_w       = (const float*)d_in[13];
  float* out = (float*)d_out;
  float* u   = (float*)d_ws;   // (T*B, H) fp32 = 128 MiB; ys overwrites in place

  const int nrows = Tn * Bn;               // 131072
  k_u   <<<nrows / 64, 256, 0, stream>>>(reward, state, last_action, W1, b1, Wih, u);
  k_scan<<<Bn,        512, 0, stream>>>(Whh_raw, hidden_in, u, out);
  k_out <<<nrows / 64, 256, 0, stream>>>(u, W2, b2, W3, b3, Qs, reward, mix_w, out);
}

// Round 3
// 2196.386 us; speedup vs baseline: 1.1148x; 1.1148x over previous
//
#include <hip/hip_runtime.h>
#include <math.h>

#define Bn 64
#define Tn 2048
#define Hn 256
#define NIc 4
#define NAc 2

constexpr float LEAK    = 0.5f;     // 1 - 1/TAU
constexpr float NEGDIAG = -0.5f;    // -1/TAU
constexpr float CLAMP_V = 1000.0f;
constexpr float EPS_V   = 1e-4f;

// raw barrier: LDS-visibility wait only, no vmcnt(0) drain of global stores
#define FAST_BARRIER() do {                                   \
    asm volatile("s_waitcnt lgkmcnt(0)" ::: "memory");        \
    __builtin_amdgcn_s_barrier();                             \
    asm volatile("" ::: "memory");                            \
  } while (0)

// ---------------------------------------------------------------------------
// K1: u[r, j] = sum_k relu( inp8[r] . W1[k] + b1[k] ) * Wih[j][k]
// ---------------------------------------------------------------------------
__global__ __launch_bounds__(256) void k_u(
    const float* __restrict__ reward, const float* __restrict__ state,
    const float* __restrict__ last_action, const float* __restrict__ W1,
    const float* __restrict__ b1, const float* __restrict__ Wih,
    float* __restrict__ u)
{
  __shared__ float inp_s[64][8];
  __shared__ float w1_s[256][8];
  __shared__ float b1_s[256];
  __shared__ __align__(16) float x_s[32][68];   // [kk][rr], padded
  __shared__ float w_s[32][257];                // [kk][j],  padded
  const int tid = threadIdx.x;
  const int r0  = blockIdx.x * 64;

  for (int idx = tid; idx < 2048; idx += 256) ((float*)w1_s)[idx] = W1[idx];
  b1_s[tid] = b1[tid];
  for (int idx = tid; idx < 512; idx += 256) {
    int rr = idx >> 3, i = idx & 7;
    int r = r0 + rr; int b = r & (Bn - 1); int t = r >> 6;
    long base = (long)b * Tn + t;
    float v;
    if (i < NAc)            v = reward[base * NAc + i];
    else if (i < NAc + NIc) v = state[base * NIc + (i - NAc)];
    else                    v = last_action[base * NAc + (i - NAc - NIc)];
    inp_s[rr][i] = v;
  }

  float acc[64];
  #pragma unroll
  for (int rr = 0; rr < 64; ++rr) acc[rr] = 0.f;

  for (int c = 0; c < 8; ++c) {
    const int k0 = c * 32;
    __syncthreads();
    for (int idx = tid; idx < 8192; idx += 256) {
      int j = idx >> 5, kk = idx & 31;
      w_s[kk][j] = Wih[j * 256 + k0 + kk];
    }
    for (int idx = tid; idx < 2048; idx += 256) {
      int kk = idx & 31, rr = idx >> 5;
      int k = k0 + kk;
      float s = b1_s[k];
      #pragma unroll
      for (int i = 0; i < 8; ++i) s = fmaf(inp_s[rr][i], w1_s[k][i], s);
      x_s[kk][rr] = fmaxf(s, 0.f);
    }
    __syncthreads();
    #pragma unroll
    for (int kk = 0; kk < 32; ++kk) {
      float wv = w_s[kk][tid];
      const float4* xp = reinterpret_cast<const float4*>(&x_s[kk][0]);
      #pragma unroll
      for (int q = 0; q < 16; ++q) {
        float4 xv = xp[q];
        acc[4*q+0] = fmaf(xv.x, wv, acc[4*q+0]);
        acc[4*q+1] = fmaf(xv.y, wv, acc[4*q+1]);
        acc[4*q+2] = fmaf(xv.z, wv, acc[4*q+2]);
        acc[4*q+3] = fmaf(xv.w, wv, acc[4*q+3]);
      }
    }
  }
  for (int rr = 0; rr < 64; ++rr)
    u[(long)(r0 + rr) * Hn + tid] = acc[rr];
}

// ---------------------------------------------------------------------------
// K2 v3: 16 waves (1024 thr). Wave w owns j in [16w,16w+16). Lane l = o*16+g
// (o in [0,4), g in [0,16)): partials for 4 outputs j = 16w+4o+m over k-slice
// [16g,16g+16). 64 FMA/lane/step; reduce-scatter over g (5 shfls); owner
// lanes (g<4, m=(b0<<1)|b1) update h, write ys. One raw barrier per step
// (no vmcnt drain). Swizzled rh: read granule rotation ((g>>1)+q)&3 -> 2-way
// (free); write side = matching row-granule permutation, conflict-free.
// ---------------------------------------------------------------------------
__global__ __launch_bounds__(1024, 4) void k_scan(
    const float* __restrict__ Whh_raw, const float* __restrict__ hidden_in,
    float* __restrict__ ubuf, float* __restrict__ out)
{
  __shared__ __align__(16) float rh[2][256];
  const int tid = threadIdx.x;
  const int w = tid >> 6;          // 0..15
  const int l = tid & 63;
  const int g = l & 15;            // k-group
  const int o = l >> 4;            // output quarter
  const int b = blockIdx.x;
  const int kbase = g << 4;

  // per-thread weights: 4 outputs x 16 k
  float wgt[4][16];
  #pragma unroll
  for (int m = 0; m < 4; ++m) {
    const int j = (w << 4) + (o << 2) + m;
    #pragma unroll
    for (int i = 0; i < 16; ++i) {
      const int k = kbase + i;
      float v = Whh_raw[j * 256 + k];
      wgt[m][i] = (k == j) ? NEGDIAG : v;
    }
  }

  const int b0 = g & 1, b1 = (g >> 1) & 1;
  const bool owner = (g < 4);
  const int m_own = (b0 << 1) | b1;
  const int j_own = (w << 4) + (o << 2) + m_own;

  // physical granule column permutation within each 16-float row:
  // logical granule (j>>2)&3 stored at (((j>>2) + (j>>5)) & 3)
  const int wr_off = (j_own & ~15) | ((((j_own >> 2) + (j_own >> 5)) & 3) << 2)
                   | (j_own & 3);

  float h = 0.f, u_cur = 0.f;
  if (owner) {
    h     = hidden_in[b * Hn + j_own];
    u_cur = ubuf[b * Hn + j_own];                              // u[t=0]
  }
  const float* u_ptr  = ubuf + ((long)Bn + b) * Hn + j_own;    // t = 1
  float*       ys_ptr = ubuf + (long)b * Hn + j_own;           // t = 0

  #pragma unroll 2
  for (int t = 0; t < Tn; ++t) {
    const int p = t & 1;
    if (owner) rh[p][wr_off] = fmaxf(h, 0.f);
    FAST_BARRIER();

    float u_nxt = 0.f;
    if (owner && t < Tn - 1) u_nxt = *u_ptr;     // 1-step-lead prefetch

    float v0 = 0.f, v1 = 0.f, v2 = 0.f, v3 = 0.f;
    const float* base = &rh[p][kbase];
    #pragma unroll
    for (int q = 0; q < 4; ++q) {
      const int rot = ((((g >> 1) + q) & 3) << 2);   // logical k = 16g+4q..+4
      const float4 r4 = *reinterpret_cast<const float4*>(base + rot);
      v0 = fmaf(r4.x, wgt[0][4*q+0], v0);
      v0 = fmaf(r4.y, wgt[0][4*q+1], v0);
      v0 = fmaf(r4.z, wgt[0][4*q+2], v0);
      v0 = fmaf(r4.w, wgt[0][4*q+3], v0);
      v1 = fmaf(r4.x, wgt[1][4*q+0], v1);
      v1 = fmaf(r4.y, wgt[1][4*q+1], v1);
      v1 = fmaf(r4.z, wgt[1][4*q+2], v1);
      v1 = fmaf(r4.w, wgt[1][4*q+3], v1);
      v2 = fmaf(r4.x, wgt[2][4*q+0], v2);
      v2 = fmaf(r4.y, wgt[2][4*q+1], v2);
      v2 = fmaf(r4.z, wgt[2][4*q+2], v2);
      v2 = fmaf(r4.w, wgt[2][4*q+3], v2);
      v3 = fmaf(r4.x, wgt[3][4*q+0], v3);
      v3 = fmaf(r4.y, wgt[3][4*q+1], v3);
      v3 = fmaf(r4.z, wgt[3][4*q+2], v3);
      v3 = fmaf(r4.w, wgt[3][4*q+3], v3);
    }

    // reduce-scatter over the 16 g-lanes:
    // stage xor1: b0=0 keeps low outputs {0,1}, b0=1 keeps high {2,3}
    const float s00 = b0 ? v0 : v2;   // send
    const float k00 = b0 ? v2 : v0;   // keep
    const float s01 = b0 ? v1 : v3;
    const float k01 = b0 ? v3 : v1;
    const float t00 = k00 + __shfl_xor(s00, 1);
    const float t01 = k01 + __shfl_xor(s01, 1);
    // stage xor2: b1=0 keeps t00 (m even), b1=1 keeps t01 (m odd)
    const float s1 = b1 ? t00 : t01;
    const float k1 = b1 ? t01 : t00;
    float s = k1 + __shfl_xor(s1, 2);
    // all-reduce remaining k-slices
    s += __shfl_xor(s, 4);
    s += __shfl_xor(s, 8);

    if (owner) {
      float hn = fmaf(LEAK, h, u_cur) + s;
      hn = fminf(fmaxf(hn, -CLAMP_V), CLAMP_V);
      *ys_ptr = hn;                                // ys in place
      h = hn; u_cur = u_nxt;
    }
    ys_ptr += Bn * Hn;
    u_ptr  += Bn * Hn;
  }
  if (owner) out[(long)Bn * Tn * NAc + b * Hn + j_own] = h;
}

// ---------------------------------------------------------------------------
// K3: v = relu(ys @ W2^T + b2); y = v @ W3^T + b3; softmax/mix epilogue.
// ---------------------------------------------------------------------------
__global__ __launch_bounds__(256) void k_out(
    const float* __restrict__ ys, const float* __restrict__ W2,
    const float* __restrict__ b2, const float* __restrict__ W3,
    const float* __restrict__ b3, const float* __restrict__ Qs,
    const float* __restrict__ reward, const float* __restrict__ mix_w,
    float* __restrict__ out)
{
  __shared__ __align__(16) float a_s[32][68];
  __shared__ float w_s[32][257];
  __shared__ float part_s[4][64][2];
  const int tid = threadIdx.x;
  const int r0  = blockIdx.x * 64;
  const float b2v = b2[tid];
  const float w3a = W3[tid];
  const float w3b = W3[256 + tid];

  float acc[64];
  #pragma unroll
  for (int rr = 0; rr < 64; ++rr) acc[rr] = 0.f;

  for (int c = 0; c < 8; ++c) {
    const int k0 = c * 32;
    __syncthreads();
    for (int idx = tid; idx < 8192; idx += 256) {
      int jj = idx >> 5, kk = idx & 31;
      w_s[kk][jj] = W2[jj * 256 + k0 + kk];
    }
    for (int idx = tid; idx < 2048; idx += 256) {
      int kk = idx & 31, rr = idx >> 5;
      a_s[kk][rr] = ys[(long)(r0 + rr) * Hn + k0 + kk];
    }
    __syncthreads();
    #pragma unroll
    for (int kk = 0; kk < 32; ++kk) {
      float wv = w_s[kk][tid];
      const float4* xp = reinterpret_cast<const float4*>(&a_s[kk][0]);
      #pragma unroll
      for (int q = 0; q < 16; ++q) {
        float4 xv = xp[q];
        acc[4*q+0] = fmaf(xv.x, wv, acc[4*q+0]);
        acc[4*q+1] = fmaf(xv.y, wv, acc[4*q+1]);
        acc[4*q+2] = fmaf(xv.z, wv, acc[4*q+2]);
        acc[4*q+3] = fmaf(xv.w, wv, acc[4*q+3]);
      }
    }
  }

  const int lane = tid & 63, wid = tid >> 6;
  for (int rr = 0; rr < 64; ++rr) {
    float v  = fmaxf(acc[rr] + b2v, 0.f);
    float p0 = v * w3a;
    float p1 = v * w3b;
    #pragma unroll
    for (int off = 32; off; off >>= 1) {
      p0 += __shfl_xor(p0, off);
      p1 += __shfl_xor(p1, off);
    }
    if (lane == 0) { part_s[wid][rr][0] = p0; part_s[wid][rr][1] = p1; }
  }
  __syncthreads();

  if (tid < 128) {
    int rr = tid >> 1, a = tid & 1;
    float y = part_s[0][rr][a] + part_s[1][rr][a]
            + part_s[2][rr][a] + part_s[3][rr][a] + b3[a];
    int r = r0 + rr;
    int t = r >> 6, b = r & (Bn - 1);
    float z = (y == 0.f) ? EPS_V : 0.f;

    float y2 = __shfl_xor(y, 1);
    float m  = fmaxf(y, y2);
    float e  = expf(y - m), e2 = expf(y2 - m);
    float sp = e / (e + e2);

    long qi = ((long)b * Tn + t) * NAc + a;
    float qv = Qs[qi];
    float q2 = __shfl_xor(qv, 1);
    float mq = fmaxf(qv, q2);
    float eq = expf(qv - mq), eq2 = expf(q2 - mq);
    float sq = eq / (eq + eq2);

    int ri = (int)reward[((long)b * Tn + t) * NAc];
    float m0 = fminf(fmaxf(mix_w[ri * 2 + 0], -1.f), 1.f);
    float m1 = fminf(fmaxf(mix_w[ri * 2 + 1], -1.f), 1.f);
    float den = fabsf(m0) + fabsf(m1);
    float sel0 = m0 / den, sel1 = m1 / den;

    float mixed = sel0 * logf(sp + z) + sel1 * logf(sq + z);
    out[((long)b * Tn + t) * NAc + a] = expf(mixed);
  }
}

// ---------------------------------------------------------------------------
extern "C" void kernel_launch(void* const* d_in, const int* in_sizes, int n_in,
                              void* d_out, int out_size, void* d_ws, size_t ws_size,
                              hipStream_t stream)
{
  const float* state       = (const float*)d_in[0];
  const float* last_action = (const float*)d_in[1];
  const float* reward      = (const float*)d_in[2];
  const float* hidden_in   = (const float*)d_in[3];
  const float* W1          = (const float*)d_in[4];
  const float* b1          = (const float*)d_in[5];
  const float* Wih         = (const float*)d_in[6];
  const float* Whh_raw     = (const float*)d_in[7];
  const float* W2          = (const float*)d_in[8];
  const float* b2          = (const float*)d_in[9];
  const float* W3          = (const float*)d_in[10];
  const float* b3          = (const float*)d_in[11];
  const float* Qs          = (const float*)d_in[12];
  const float* mix_w       = (const float*)d_in[13];
  float* out = (float*)d_out;
  float* u   = (float*)d_ws;   // (T*B, H) fp32 = 128 MiB; ys overwrites in place

  const int nrows = Tn * Bn;               // 131072
  k_u   <<<nrows / 64, 256, 0, stream>>>(reward, state, last_action, W1, b1, Wih, u);
  k_scan<<<Bn,       1024, 0, stream>>>(Whh_raw, hidden_in, u, out);
  k_out <<<nrows / 64, 256, 0, stream>>>(u, W2, b2, W3, b3, Qs, reward, mix_w, out);
}

// Round 4
// 1700.149 us; speedup vs baseline: 1.4402x; 1.2919x over previous
//
#include <hip/hip_runtime.h>
#include <hip/hip_bf16.h>
#include <math.h>

#define Bn 64
#define Tn 2048
#define Hn 256

constexpr float LEAK    = 0.5f;     // 1 - 1/TAU
constexpr float NEGDIAG = -0.5f;    // -1/TAU
constexpr float CLAMP_V = 1000.0f;
constexpr float EPS_V   = 1e-4f;

typedef __attribute__((ext_vector_type(8))) short  short8;  // 8 bf16 (4 VGPR)
typedef __attribute__((ext_vector_type(4))) float  f32x4;

#define FAST_BARRIER() do {                                   \
    asm volatile("s_waitcnt lgkmcnt(0)" ::: "memory");        \
    __builtin_amdgcn_s_barrier();                             \
    asm volatile("" ::: "memory");                            \
  } while (0)

__device__ inline short bf16_rne(float x) {
  __hip_bfloat16 h = __float2bfloat16(x);
  return *reinterpret_cast<short*>(&h);
}
__device__ inline float bf16_to_f(short s) {
  union { unsigned u; float f; } c; c.u = ((unsigned)(unsigned short)s) << 16;
  return c.f;
}
__device__ inline unsigned pack2(short a, short b) {
  return (unsigned)(unsigned short)a | ((unsigned)(unsigned short)b << 16);
}

// LDS row stride for bf16 tiles: 32 k + 8 pad = 40 shorts (80 B, 16B-multiple)
#define SA 40

// ---------------------------------------------------------------------------
// G1: u = relu(inp8 @ W1^T + b1) @ Wih^T, MFMA bf16 hi/lo.
// Tile 128(M) x 256(N), BK=32, 8 waves (2m x 4n), each wave 64x64.
// A (=x) computed on the fly fp32 then split hi/lo; B (=Wih) split on the fly.
// ---------------------------------------------------------------------------
__global__ __launch_bounds__(512) void g_u(
    const float* __restrict__ reward, const float* __restrict__ state,
    const float* __restrict__ last_action, const float* __restrict__ W1,
    const float* __restrict__ b1, const float* __restrict__ Wih,
    float* __restrict__ u)
{
  __shared__ short Ah[128*SA], Al[128*SA], Bh[256*SA], Bl[256*SA];
  __shared__ __align__(16) float inp_s[128][8];
  __shared__ __align__(16) float w1_s[256][8];
  __shared__ float b1_s[256];
  const int tid = threadIdx.x;
  const int r0  = blockIdx.x * 128;

  for (int idx = tid; idx < 2048; idx += 512) ((float*)w1_s)[idx] = W1[idx];
  if (tid < 256) b1_s[tid] = b1[tid];
  for (int idx = tid; idx < 1024; idx += 512) {
    int rr = idx >> 3, i = idx & 7;
    int r = r0 + rr, b = r & 63, t = r >> 6;
    long base = (long)b * Tn + t;
    float v;
    if (i < 2)      v = reward[base * 2 + i];
    else if (i < 6) v = state[base * 4 + (i - 2)];
    else            v = last_action[base * 2 + (i - 6)];
    inp_s[rr][i] = v;
  }

  const int w    = tid >> 6, lane = tid & 63;
  const int wm   = w >> 2, wn = w & 3;
  const int fr   = lane & 15, fk = lane >> 4;
  f32x4 acc[4][4];
  #pragma unroll
  for (int a = 0; a < 4; ++a)
    #pragma unroll
    for (int c = 0; c < 4; ++c) acc[a][c] = (f32x4){0.f, 0.f, 0.f, 0.f};

  __syncthreads();

  for (int ks = 0; ks < 8; ++ks) {
    const int k0 = ks * 32;
    if (ks) __syncthreads();
    // ---- stage A: x[128][32] on the fly, hi/lo bf16 (2 k per slot) ----
    for (int p = tid; p < 2048; p += 512) {
      int rr = p >> 4, kp = (p & 15) * 2;
      int k = k0 + kp;
      float4 iv0 = *reinterpret_cast<const float4*>(&inp_s[rr][0]);
      float4 iv1 = *reinterpret_cast<const float4*>(&inp_s[rr][4]);
      float4 wa0 = *reinterpret_cast<const float4*>(&w1_s[k][0]);
      float4 wa1 = *reinterpret_cast<const float4*>(&w1_s[k][4]);
      float4 wb0 = *reinterpret_cast<const float4*>(&w1_s[k+1][0]);
      float4 wb1 = *reinterpret_cast<const float4*>(&w1_s[k+1][4]);
      float s0 = b1_s[k], s1 = b1_s[k+1];
      s0 = fmaf(iv0.x, wa0.x, s0); s0 = fmaf(iv0.y, wa0.y, s0);
      s0 = fmaf(iv0.z, wa0.z, s0); s0 = fmaf(iv0.w, wa0.w, s0);
      s0 = fmaf(iv1.x, wa1.x, s0); s0 = fmaf(iv1.y, wa1.y, s0);
      s0 = fmaf(iv1.z, wa1.z, s0); s0 = fmaf(iv1.w, wa1.w, s0);
      s1 = fmaf(iv0.x, wb0.x, s1); s1 = fmaf(iv0.y, wb0.y, s1);
      s1 = fmaf(iv0.z, wb0.z, s1); s1 = fmaf(iv0.w, wb0.w, s1);
      s1 = fmaf(iv1.x, wb1.x, s1); s1 = fmaf(iv1.y, wb1.y, s1);
      s1 = fmaf(iv1.z, wb1.z, s1); s1 = fmaf(iv1.w, wb1.w, s1);
      float v0 = fmaxf(s0, 0.f), v1 = fmaxf(s1, 0.f);
      short h0 = bf16_rne(v0), h1 = bf16_rne(v1);
      short l0 = bf16_rne(v0 - bf16_to_f(h0)), l1 = bf16_rne(v1 - bf16_to_f(h1));
      int off = rr * SA + kp;
      *reinterpret_cast<unsigned*>(&Ah[off]) = pack2(h0, h1);
      *reinterpret_cast<unsigned*>(&Al[off]) = pack2(l0, l1);
    }
    // ---- stage B: Wih[256][32] hi/lo ----
    for (int c = tid; c < 2048; c += 512) {
      int n = c >> 3, kc = (c & 7) * 4;
      float4 f = *reinterpret_cast<const float4*>(&Wih[n * 256 + k0 + kc]);
      short h0 = bf16_rne(f.x), h1 = bf16_rne(f.y), h2 = bf16_rne(f.z), h3 = bf16_rne(f.w);
      short l0 = bf16_rne(f.x - bf16_to_f(h0)), l1 = bf16_rne(f.y - bf16_to_f(h1));
      short l2 = bf16_rne(f.z - bf16_to_f(h2)), l3 = bf16_rne(f.w - bf16_to_f(h3));
      int off = n * SA + kc;
      *reinterpret_cast<uint2*>(&Bh[off]) = make_uint2(pack2(h0, h1), pack2(h2, h3));
      *reinterpret_cast<uint2*>(&Bl[off]) = make_uint2(pack2(l0, l1), pack2(l2, l3));
    }
    __syncthreads();
    // ---- fragments + MFMA ----
    short8 bhf[4], blf[4];
    #pragma unroll
    for (int nf = 0; nf < 4; ++nf) {
      const int brow = wn * 64 + nf * 16 + fr;
      bhf[nf] = *reinterpret_cast<const short8*>(&Bh[brow * SA + fk * 8]);
      blf[nf] = *reinterpret_cast<const short8*>(&Bl[brow * SA + fk * 8]);
    }
    #pragma unroll
    for (int mf = 0; mf < 4; ++mf) {
      const int arow = wm * 64 + mf * 16 + fr;
      short8 ah = *reinterpret_cast<const short8*>(&Ah[arow * SA + fk * 8]);
      short8 al = *reinterpret_cast<const short8*>(&Al[arow * SA + fk * 8]);
      #pragma unroll
      for (int nf = 0; nf < 4; ++nf) {
        acc[mf][nf] = __builtin_amdgcn_mfma_f32_16x16x32_bf16(ah, bhf[nf], acc[mf][nf], 0, 0, 0);
        acc[mf][nf] = __builtin_amdgcn_mfma_f32_16x16x32_bf16(ah, blf[nf], acc[mf][nf], 0, 0, 0);
        acc[mf][nf] = __builtin_amdgcn_mfma_f32_16x16x32_bf16(al, bhf[nf], acc[mf][nf], 0, 0, 0);
      }
    }
  }
  // ---- epilogue: write u fp32 (C layout: col=lane&15, row=(lane>>4)*4+j) ----
  #pragma unroll
  for (int mf = 0; mf < 4; ++mf) {
    const int rbase = r0 + wm * 64 + mf * 16 + (lane >> 4) * 4;
    #pragma unroll
    for (int nf = 0; nf < 4; ++nf) {
      const int n = wn * 64 + nf * 16 + fr;
      #pragma unroll
      for (int j = 0; j < 4; ++j)
        u[(long)(rbase + j) * Hn + n] = acc[mf][nf][j];
    }
  }
}

// ---------------------------------------------------------------------------
// K2 (unchanged from round 3): 16-wave scan, 1 raw barrier/step.
// ---------------------------------------------------------------------------
__global__ __launch_bounds__(1024, 4) void k_scan(
    const float* __restrict__ Whh_raw, const float* __restrict__ hidden_in,
    float* __restrict__ ubuf, float* __restrict__ out)
{
  __shared__ __align__(16) float rh[2][256];
  const int tid = threadIdx.x;
  const int w = tid >> 6;
  const int l = tid & 63;
  const int g = l & 15;
  const int o = l >> 4;
  const int b = blockIdx.x;
  const int kbase = g << 4;

  float wgt[4][16];
  #pragma unroll
  for (int m = 0; m < 4; ++m) {
    const int j = (w << 4) + (o << 2) + m;
    #pragma unroll
    for (int i = 0; i < 16; ++i) {
      const int k = kbase + i;
      float v = Whh_raw[j * 256 + k];
      wgt[m][i] = (k == j) ? NEGDIAG : v;
    }
  }

  const int b0 = g & 1, b1 = (g >> 1) & 1;
  const bool owner = (g < 4);
  const int m_own = (b0 << 1) | b1;
  const int j_own = (w << 4) + (o << 2) + m_own;

  const int wr_off = (j_own & ~15) | ((((j_own >> 2) + (j_own >> 5)) & 3) << 2)
                   | (j_own & 3);

  float h = 0.f, u_cur = 0.f;
  if (owner) {
    h     = hidden_in[b * Hn + j_own];
    u_cur = ubuf[b * Hn + j_own];
  }
  const float* u_ptr  = ubuf + ((long)Bn + b) * Hn + j_own;
  float*       ys_ptr = ubuf + (long)b * Hn + j_own;

  #pragma unroll 2
  for (int t = 0; t < Tn; ++t) {
    const int p = t & 1;
    if (owner) rh[p][wr_off] = fmaxf(h, 0.f);
    FAST_BARRIER();

    float u_nxt = 0.f;
    if (owner && t < Tn - 1) u_nxt = *u_ptr;

    float v0 = 0.f, v1 = 0.f, v2 = 0.f, v3 = 0.f;
    const float* base = &rh[p][kbase];
    #pragma unroll
    for (int q = 0; q < 4; ++q) {
      const int rot = ((((g >> 1) + q) & 3) << 2);
      const float4 r4 = *reinterpret_cast<const float4*>(base + rot);
      v0 = fmaf(r4.x, wgt[0][4*q+0], v0);
      v0 = fmaf(r4.y, wgt[0][4*q+1], v0);
      v0 = fmaf(r4.z, wgt[0][4*q+2], v0);
      v0 = fmaf(r4.w, wgt[0][4*q+3], v0);
      v1 = fmaf(r4.x, wgt[1][4*q+0], v1);
      v1 = fmaf(r4.y, wgt[1][4*q+1], v1);
      v1 = fmaf(r4.z, wgt[1][4*q+2], v1);
      v1 = fmaf(r4.w, wgt[1][4*q+3], v1);
      v2 = fmaf(r4.x, wgt[2][4*q+0], v2);
      v2 = fmaf(r4.y, wgt[2][4*q+1], v2);
      v2 = fmaf(r4.z, wgt[2][4*q+2], v2);
      v2 = fmaf(r4.w, wgt[2][4*q+3], v2);
      v3 = fmaf(r4.x, wgt[3][4*q+0], v3);
      v3 = fmaf(r4.y, wgt[3][4*q+1], v3);
      v3 = fmaf(r4.z, wgt[3][4*q+2], v3);
      v3 = fmaf(r4.w, wgt[3][4*q+3], v3);
    }

    const float s00 = b0 ? v0 : v2;
    const float k00 = b0 ? v2 : v0;
    const float s01 = b0 ? v1 : v3;
    const float k01 = b0 ? v3 : v1;
    const float t00 = k00 + __shfl_xor(s00, 1);
    const float t01 = k01 + __shfl_xor(s01, 1);
    const float s1 = b1 ? t00 : t01;
    const float k1 = b1 ? t01 : t00;
    float s = k1 + __shfl_xor(s1, 2);
    s += __shfl_xor(s, 4);
    s += __shfl_xor(s, 8);

    if (owner) {
      float hn = fmaf(LEAK, h, u_cur) + s;
      hn = fminf(fmaxf(hn, -CLAMP_V), CLAMP_V);
      *ys_ptr = hn;
      h = hn; u_cur = u_nxt;
    }
    ys_ptr += Bn * Hn;
    u_ptr  += Bn * Hn;
  }
  if (owner) out[(long)Bn * Tn * 2 + b * Hn + j_own] = h;
}

// ---------------------------------------------------------------------------
// G2: v = relu(ys @ W2^T + b2); y = v @ W3^T  (pre-b3) -> d_out y-region.
// Same MFMA structure as G1; A = ys fp32 split on the fly.
// ---------------------------------------------------------------------------
__global__ __launch_bounds__(512) void g_out(
    const float* __restrict__ ys, const float* __restrict__ W2,
    const float* __restrict__ b2, const float* __restrict__ W3,
    float* __restrict__ yout)
{
  __shared__ short Ah[128*SA], Al[128*SA], Bh[256*SA], Bl[256*SA];
  __shared__ float b2_s[256];
  __shared__ float w3_s[512];
  const int tid = threadIdx.x;
  const int r0  = blockIdx.x * 128;

  if (tid < 256) b2_s[tid] = b2[tid];
  if (tid < 512) w3_s[tid] = W3[tid];

  const int w    = tid >> 6, lane = tid & 63;
  const int wm   = w >> 2, wn = w & 3;
  const int fr   = lane & 15, fk = lane >> 4;
  f32x4 acc[4][4];
  #pragma unroll
  for (int a = 0; a < 4; ++a)
    #pragma unroll
    for (int c = 0; c < 4; ++c) acc[a][c] = (f32x4){0.f, 0.f, 0.f, 0.f};

  __syncthreads();

  for (int ks = 0; ks < 8; ++ks) {
    const int k0 = ks * 32;
    if (ks) __syncthreads();
    // ---- stage A: ys[128][32] fp32 -> hi/lo ----
    for (int c = tid; c < 1024; c += 512) {
      int rr = c >> 3, kc = (c & 7) * 4;
      float4 f = *reinterpret_cast<const float4*>(&ys[(long)(r0 + rr) * Hn + k0 + kc]);
      short h0 = bf16_rne(f.x), h1 = bf16_rne(f.y), h2 = bf16_rne(f.z), h3 = bf16_rne(f.w);
      short l0 = bf16_rne(f.x - bf16_to_f(h0)), l1 = bf16_rne(f.y - bf16_to_f(h1));
      short l2 = bf16_rne(f.z - bf16_to_f(h2)), l3 = bf16_rne(f.w - bf16_to_f(h3));
      int off = rr * SA + kc;
      *reinterpret_cast<uint2*>(&Ah[off]) = make_uint2(pack2(h0, h1), pack2(h2, h3));
      *reinterpret_cast<uint2*>(&Al[off]) = make_uint2(pack2(l0, l1), pack2(l2, l3));
    }
    // ---- stage B: W2[256][32] hi/lo ----
    for (int c = tid; c < 2048; c += 512) {
      int n = c >> 3, kc = (c & 7) * 4;
      float4 f = *reinterpret_cast<const float4*>(&W2[n * 256 + k0 + kc]);
      short h0 = bf16_rne(f.x), h1 = bf16_rne(f.y), h2 = bf16_rne(f.z), h3 = bf16_rne(f.w);
      short l0 = bf16_rne(f.x - bf16_to_f(h0)), l1 = bf16_rne(f.y - bf16_to_f(h1));
      short l2 = bf16_rne(f.z - bf16_to_f(h2)), l3 = bf16_rne(f.w - bf16_to_f(h3));
      int off = n * SA + kc;
      *reinterpret_cast<uint2*>(&Bh[off]) = make_uint2(pack2(h0, h1), pack2(h2, h3));
      *reinterpret_cast<uint2*>(&Bl[off]) = make_uint2(pack2(l0, l1), pack2(l2, l3));
    }
    __syncthreads();
    short8 bhf[4], blf[4];
    #pragma unroll
    for (int nf = 0; nf < 4; ++nf) {
      const int brow = wn * 64 + nf * 16 + fr;
      bhf[nf] = *reinterpret_cast<const short8*>(&Bh[brow * SA + fk * 8]);
      blf[nf] = *reinterpret_cast<const short8*>(&Bl[brow * SA + fk * 8]);
    }
    #pragma unroll
    for (int mf = 0; mf < 4; ++mf) {
      const int arow = wm * 64 + mf * 16 + fr;
      short8 ah = *reinterpret_cast<const short8*>(&Ah[arow * SA + fk * 8]);
      short8 al = *reinterpret_cast<const short8*>(&Al[arow * SA + fk * 8]);
      #pragma unroll
      for (int nf = 0; nf < 4; ++nf) {
        acc[mf][nf] = __builtin_amdgcn_mfma_f32_16x16x32_bf16(ah, bhf[nf], acc[mf][nf], 0, 0, 0);
        acc[mf][nf] = __builtin_amdgcn_mfma_f32_16x16x32_bf16(ah, blf[nf], acc[mf][nf], 0, 0, 0);
        acc[mf][nf] = __builtin_amdgcn_mfma_f32_16x16x32_bf16(al, bhf[nf], acc[mf][nf], 0, 0, 0);
      }
    }
  }

  // ---- epilogue: v=relu(acc+b2); yp = v . W3 per row; reduce; write y ----
  float yp[4][4][2];
  #pragma unroll
  for (int mf = 0; mf < 4; ++mf)
    #pragma unroll
    for (int j = 0; j < 4; ++j) { yp[mf][j][0] = 0.f; yp[mf][j][1] = 0.f; }

  #pragma unroll
  for (int mf = 0; mf < 4; ++mf)
    #pragma unroll
    for (int nf = 0; nf < 4; ++nf) {
      const int n = wn * 64 + nf * 16 + fr;
      const float b2v = b2_s[n];
      const float w30 = w3_s[n], w31 = w3_s[256 + n];
      #pragma unroll
      for (int j = 0; j < 4; ++j) {
        float v = fmaxf(acc[mf][nf][j] + b2v, 0.f);
        yp[mf][j][0] = fmaf(v, w30, yp[mf][j][0]);
        yp[mf][j][1] = fmaf(v, w31, yp[mf][j][1]);
      }
    }
  #pragma unroll
  for (int off = 1; off < 16; off <<= 1) {
    #pragma unroll
    for (int mf = 0; mf < 4; ++mf)
      #pragma unroll
      for (int j = 0; j < 4; ++j) {
        yp[mf][j][0] += __shfl_xor(yp[mf][j][0], off);
        yp[mf][j][1] += __shfl_xor(yp[mf][j][1], off);
      }
  }

  __syncthreads();                       // all LDS frag reads done
  float* yred = reinterpret_cast<float*>(Ah);   // [128][2][4 wn]
  if (fr == 0) {
    #pragma unroll
    for (int mf = 0; mf < 4; ++mf)
      #pragma unroll
      for (int j = 0; j < 4; ++j) {
        int rl = wm * 64 + mf * 16 + (lane >> 4) * 4 + j;
        yred[(rl * 2 + 0) * 4 + wn] = yp[mf][j][0];
        yred[(rl * 2 + 1) * 4 + wn] = yp[mf][j][1];
      }
  }
  __syncthreads();
  if (tid < 256) {
    int rl = tid >> 1, a = tid & 1;
    const float* yr = &yred[(rl * 2 + a) * 4];
    float y = (yr[0] + yr[1]) + (yr[2] + yr[3]);
    int r = r0 + rl, b = r & 63, t = r >> 6;
    yout[((long)b * Tn + t) * 2 + a] = y;
  }
}

// ---------------------------------------------------------------------------
// Head: y -> softmax/mix -> out, in place on d_out's y region.
// ---------------------------------------------------------------------------
__global__ __launch_bounds__(256) void k_head(
    float* __restrict__ out, const float* __restrict__ Qs,
    const float* __restrict__ reward, const float* __restrict__ mix_w,
    const float* __restrict__ b3)
{
  const int idx = blockIdx.x * 256 + threadIdx.x;   // b*Tn + t
  if (idx >= Bn * Tn) return;
  const long base = (long)idx * 2;
  float y0 = out[base]     + b3[0];
  float y1 = out[base + 1] + b3[1];
  float z0 = (y0 == 0.f) ? EPS_V : 0.f;
  float z1 = (y1 == 0.f) ? EPS_V : 0.f;

  float m  = fmaxf(y0, y1);
  float e0 = expf(y0 - m), e1 = expf(y1 - m), es = e0 + e1;
  float sp0 = e0 / es, sp1 = e1 / es;

  float q0 = Qs[base], q1 = Qs[base + 1];
  float mq = fmaxf(q0, q1);
  float f0 = expf(q0 - mq), f1 = expf(q1 - mq), fs = f0 + f1;
  float sq0 = f0 / fs, sq1 = f1 / fs;

  int ri = (int)reward[base];
  float m0 = fminf(fmaxf(mix_w[ri * 2 + 0], -1.f), 1.f);
  float m1 = fminf(fmaxf(mix_w[ri * 2 + 1], -1.f), 1.f);
  float den = fabsf(m0) + fabsf(m1);
  float s0 = m0 / den, s1 = m1 / den;

  out[base]     = expf(s0 * logf(sp0 + z0) + s1 * logf(sq0 + z0));
  out[base + 1] = expf(s0 * logf(sp1 + z1) + s1 * logf(sq1 + z1));
}

// ---------------------------------------------------------------------------
extern "C" void kernel_launch(void* const* d_in, const int* in_sizes, int n_in,
                              void* d_out, int out_size, void* d_ws, size_t ws_size,
                              hipStream_t stream)
{
  const float* state       = (const float*)d_in[0];
  const float* last_action = (const float*)d_in[1];
  const float* reward      = (const float*)d_in[2];
  const float* hidden_in   = (const float*)d_in[3];
  const float* W1          = (const float*)d_in[4];
  const float* b1          = (const float*)d_in[5];
  const float* Wih         = (const float*)d_in[6];
  const float* Whh_raw     = (const float*)d_in[7];
  const float* W2          = (const float*)d_in[8];
  const float* b2          = (const float*)d_in[9];
  const float* W3          = (const float*)d_in[10];
  const float* b3          = (const float*)d_in[11];
  const float* Qs          = (const float*)d_in[12];
  const float* mix_w       = (const float*)d_in[13];
  float* out = (float*)d_out;
  float* u   = (float*)d_ws;   // (T*B, H) fp32 = 128 MiB; ys overwrites in place

  const int nrows = Tn * Bn;                 // 131072
  g_u   <<<nrows / 128, 512, 0, stream>>>(reward, state, last_action, W1, b1, Wih, u);
  k_scan<<<Bn,          1024, 0, stream>>>(Whh_raw, hidden_in, u, out);
  g_out <<<nrows / 128, 512, 0, stream>>>(u, W2, b2, W3, out);
  k_head<<<nrows / 256, 256, 0, stream>>>(out, Qs, reward, mix_w, b3);
}